// Round 2
// baseline (461.057 us; speedup 1.0000x reference)
//
#include <hip/hip_runtime.h>
#include <hip/hip_bf16.h>
#include <cstdint>

typedef unsigned short u16;
typedef __attribute__((ext_vector_type(8))) short bf16x8;
typedef __attribute__((ext_vector_type(4))) float f32x4;

#define BATCH 4
#define CDIM 256
#define NTOK 4096   // H*W

__device__ inline float fexp2(float x) { return __builtin_amdgcn_exp2f(x); }

__device__ inline u16 f2bf(float f) {
  union { float f; uint32_t u; } un; un.f = f;
  uint32_t u = un.u;
  u += 0x7fffu + ((u >> 16) & 1u);
  return (u16)(u >> 16);
}
__device__ inline float bf2f(u16 h) {
  union { uint32_t u; float f; } un; un.u = ((uint32_t)h) << 16; return un.f;
}

// ---------------------------------------------------------------------------
// LayerNorm: x [B, C, N] -> xn bf16 [B*N, C]
// ---------------------------------------------------------------------------
__global__ __launch_bounds__(256) void ln_kernel(const float* __restrict__ x,
                                                 const float* __restrict__ gamma,
                                                 const float* __restrict__ beta,
                                                 u16* __restrict__ xn) {
  __shared__ float tile[CDIM][33];
  __shared__ float reds[8][32];
  __shared__ float reds2[8][32];
  __shared__ float mu_s[32], rs_s[32];

  int b  = blockIdx.x >> 7;
  int n0 = (blockIdx.x & 127) * 32;
  const float* xb = x + (size_t)b * CDIM * NTOK;

  int t = threadIdx.x & 31;
  int g = threadIdx.x >> 5;

  for (int c = g; c < CDIM; c += 8)
    tile[c][t] = xb[(size_t)c * NTOK + n0 + t];
  __syncthreads();

  float s = 0.f, s2 = 0.f;
  for (int c = g * 32; c < g * 32 + 32; ++c) {
    float v = tile[c][t];
    s += v; s2 += v * v;
  }
  reds[g][t] = s; reds2[g][t] = s2;
  __syncthreads();
  if (threadIdx.x < 32) {
    float ts = 0.f, ts2 = 0.f;
    for (int gg = 0; gg < 8; ++gg) { ts += reds[gg][threadIdx.x]; ts2 += reds2[gg][threadIdx.x]; }
    float mu = ts / CDIM;
    float var = ts2 / CDIM - mu * mu;
    mu_s[threadIdx.x] = mu;
    rs_s[threadIdx.x] = rsqrtf(var + 1e-5f);
  }
  __syncthreads();

  int c = threadIdx.x;
  float gam = gamma[c], bet = beta[c];
  u16* out = xn + ((size_t)b * NTOK + n0) * CDIM;
  for (int tt = 0; tt < 32; ++tt) {
    float v = tile[c][tt];
    float y = (v - mu_s[tt]) * rs_s[tt] * gam + bet;
    out[(size_t)tt * CDIM + c] = f2bf(y);
  }
}

// ---------------------------------------------------------------------------
// W [K, Cout] fp32 -> WT bf16 [Cout, K], optional scale (log2e for Wq)
// ---------------------------------------------------------------------------
__global__ __launch_bounds__(256) void wt_kernel(const float* __restrict__ W,
                                                 u16* __restrict__ WT,
                                                 float scale) {
  __shared__ float tile[32][33];
  int i0 = blockIdx.y * 32;
  int j0 = blockIdx.x * 32;
  int tx = threadIdx.x, ty = threadIdx.y;
  for (int r = ty; r < 32; r += 8)
    tile[r][tx] = W[(size_t)(i0 + r) * CDIM + j0 + tx];
  __syncthreads();
  for (int r = ty; r < 32; r += 8)
    WT[(size_t)(j0 + r) * CDIM + i0 + tx] = f2bf(tile[tx][r] * scale);
}

// ---------------------------------------------------------------------------
// Fused QKV projection (unchanged)
// ---------------------------------------------------------------------------
__global__ __launch_bounds__(256) void qkv_kernel(const u16* __restrict__ A,
                                                  const u16* __restrict__ B3,
                                                  u16* __restrict__ Qb,
                                                  u16* __restrict__ Kb,
                                                  u16* __restrict__ VT) {
  constexpr int BM = 128, BN = 64, BK = 32;
  __shared__ u16 shA[BM][BK + 8];
  __shared__ u16 shB[BN][BK + 8];

  int m0 = blockIdx.y * BM;
  int n0 = blockIdx.x * BN;

  int tid  = threadIdx.x;
  int lane = tid & 63;
  int wave = tid >> 6;
  int wm = wave >> 1, wn = wave & 1;
  int col  = lane & 15;
  int quad = lane >> 4;

  f32x4 acc[4][2];
#pragma unroll
  for (int i = 0; i < 4; ++i)
#pragma unroll
    for (int j = 0; j < 2; ++j) acc[i][j] = (f32x4){0.f, 0.f, 0.f, 0.f};

  for (int kb = 0; kb < CDIM; kb += BK) {
    __syncthreads();
#pragma unroll
    for (int c = tid; c < BM * BK / 8; c += 256) {
      int row = c >> 2, kc = c & 3;
      *(uint4*)&shA[row][kc * 8] = *(const uint4*)&A[(size_t)(m0 + row) * CDIM + kb + kc * 8];
    }
#pragma unroll
    for (int c = tid; c < BN * BK / 8; c += 256) {
      int row = c >> 2, kc = c & 3;
      *(uint4*)&shB[row][kc * 8] = *(const uint4*)&B3[(size_t)(n0 + row) * CDIM + kb + kc * 8];
    }
    __syncthreads();

    bf16x8 af[4], bfv[2];
#pragma unroll
    for (int i = 0; i < 4; ++i)
      af[i] = *(const bf16x8*)&shA[wm * 64 + i * 16 + col][quad * 8];
#pragma unroll
    for (int j = 0; j < 2; ++j)
      bfv[j] = *(const bf16x8*)&shB[wn * 32 + j * 16 + col][quad * 8];
#pragma unroll
    for (int i = 0; i < 4; ++i)
#pragma unroll
      for (int j = 0; j < 2; ++j)
        acc[i][j] = __builtin_amdgcn_mfma_f32_16x16x32_bf16(af[i], bfv[j], acc[i][j], 0, 0, 0);
  }

  int mode = n0 >> 8;   // 0:Q 1:K 2:V (block-uniform)
  int r0 = quad * 4;
#pragma unroll
  for (int i = 0; i < 4; ++i) {
    int mbase = m0 + wm * 64 + i * 16 + r0;
#pragma unroll
    for (int j = 0; j < 2; ++j) {
      int n = n0 + wn * 32 + j * 16 + col;
#pragma unroll
      for (int r = 0; r < 4; ++r) {
        int m = mbase + r;
        float v = acc[i][j][r];
        if (mode == 0) {
          Qb[(size_t)m * CDIM + n] = f2bf(v);
        } else if (mode == 1) {
          Kb[(size_t)m * CDIM + (n - 256)] = f2bf(v);
        } else {
          int cv = n - 512, bb = m >> 12, nt = m & 4095;
          VT[((size_t)bb * CDIM + cv) * NTOK + nt] = f2bf(v);
        }
      }
    }
  }
}

// ---------------------------------------------------------------------------
// Fused attention, TWO-PASS exact softmax, DIRECT-FROM-L2 operands:
//  - No LDS staging of K/V: MFMA B-frags are contiguous 16B/lane in global
//    (K row-major [n][c] for S; VT [c][n] for PV); per-batch K+V = 4MB sits
//    in the XCD L2 (XCD swizzle pins same-batch blocks to one XCD).
//  - 4-way key split across waves (zero redundant loads); each wave holds
//    BOTH q-groups' Q frags and computes S[32q x 16keys] / O[32q x 64ch].
//  - Pass 1 is barrier-free (reg double-buffered K pipeline).
//  - Pass 2: one raw s_barrier per 64-key tile (lgkmcnt-only drain); P
//    handoff via two 4KB XOR-swizzled LDS buffers; K/V loads for t+1 stay
//    in flight across the barrier (vmcnt never drained in-loop).
// ---------------------------------------------------------------------------
__global__ __launch_bounds__(256, 2) void fa_kernel(const u16* __restrict__ Qg,
                                                    const u16* __restrict__ Kg,
                                                    const u16* __restrict__ Vtg,
                                                    const u16* __restrict__ xng,
                                                    const float* __restrict__ w1p,
                                                    const float* __restrict__ w2p,
                                                    float* __restrict__ outg) {
  // epilogue otile [256][36] f32 = 36864 B dominates; P/stat usage is smaller
  __shared__ __align__(16) char smem[36864];
  float* otile = (float*)smem;
  u16* Pb0 = (u16*)smem;                 // [32][64] bf16, 16B-slot XOR swizzle
  u16* Pb1 = Pb0 + 2048;
  float* mbuf = (float*)(smem + 8192);   // [4 waves][32 q]
  float* lbuf = mbuf + 128;

  int b  = blockIdx.x & 3;               // XCD swizzle: same XCD -> same batch
  int q0 = (blockIdx.x >> 2) * 32;

  const u16* Q  = Qg  + (size_t)b * NTOK * CDIM;
  const u16* K  = Kg  + (size_t)b * NTOK * CDIM;
  const u16* Vt = Vtg + (size_t)b * NTOK * CDIM;

  int tid  = threadIdx.x;
  int lane = tid & 63;
  int w    = tid >> 6;                   // wave = key quarter
  int col = lane & 15, quad = lane >> 4;

  float e1 = __expf(w1p[0]), e2 = __expf(w2p[0]);
  float a1 = e1 / (e1 + e2), a2 = e2 / (e1 + e2);
  float a2p = a2 * 0.4804530139182014f;  // a2 * ln2^2 (S in exp2 domain)

  // ---- Q A-frags for BOTH q-groups (64 VGPR), live through both passes ----
  bf16x8 aq[2][8];
#pragma unroll
  for (int g = 0; g < 2; ++g)
#pragma unroll
    for (int kk = 0; kk < 8; ++kk)
      aq[g][kk] = *(const bf16x8*)&Q[(size_t)(q0 + g * 16 + col) * CDIM + kk * 32 + quad * 8];

  // per-lane global bases: K rows = keys (this wave's 16), VT rows = channels
  const u16* kbase = K  + (size_t)(w * 16 + col) * CDIM + quad * 8;
  const u16* vbase = Vt + (size_t)(w * 64 + col) * NTOK + quad * 8;

  // =========================== PASS 1: m, l ================================
  float ml[2][4], ll[2][4];
#pragma unroll
  for (int g = 0; g < 2; ++g)
#pragma unroll
    for (int r = 0; r < 4; ++r) { ml[g][r] = -3e38f; ll[g][r] = 0.f; }

  auto p1step = [&](const bf16x8* kf) {
    f32x4 s[2];
    s[0] = (f32x4){0.f, 0.f, 0.f, 0.f};
    s[1] = (f32x4){0.f, 0.f, 0.f, 0.f};
#pragma unroll
    for (int kk = 0; kk < 8; ++kk) {
      s[0] = __builtin_amdgcn_mfma_f32_16x16x32_bf16(aq[0][kk], kf[kk], s[0], 0, 0, 0);
      s[1] = __builtin_amdgcn_mfma_f32_16x16x32_bf16(aq[1][kk], kf[kk], s[1], 0, 0, 0);
    }
    float mnew[2][4];
    bool chg = false;
#pragma unroll
    for (int g = 0; g < 2; ++g)
#pragma unroll
      for (int r = 0; r < 4; ++r) {
        float mn = fmaxf(ml[g][r], s[g][r]);
        mnew[g][r] = mn;
        chg = chg || (mn > ml[g][r]);
      }
    if (__any(chg)) {
#pragma unroll
      for (int g = 0; g < 2; ++g)
#pragma unroll
        for (int r = 0; r < 4; ++r) {
          ll[g][r] = ll[g][r] * fexp2(ml[g][r] - mnew[g][r]) + fexp2(s[g][r] - mnew[g][r]);
          ml[g][r] = mnew[g][r];
        }
    } else {
#pragma unroll
      for (int g = 0; g < 2; ++g)
#pragma unroll
        for (int r = 0; r < 4; ++r)
          ll[g][r] += fexp2(s[g][r] - ml[g][r]);
    }
  };

  bf16x8 kf0[8], kf1[8];
#pragma unroll
  for (int kk = 0; kk < 8; ++kk)
    kf0[kk] = *(const bf16x8*)(kbase + kk * 32);

  for (int t = 0; t < 64; t += 2) {
#pragma unroll
    for (int kk = 0; kk < 8; ++kk)
      kf1[kk] = *(const bf16x8*)(kbase + (size_t)(t + 1) * 16384 + kk * 32);
    p1step(kf0);
    if (t + 2 < 64) {
#pragma unroll
      for (int kk = 0; kk < 8; ++kk)
        kf0[kk] = *(const bf16x8*)(kbase + (size_t)(t + 2) * 16384 + kk * 32);
    }
    p1step(kf1);
  }

  // merge across the 16 cols of this wave (keys within quarter)
#pragma unroll
  for (int off = 1; off < 16; off <<= 1)
#pragma unroll
    for (int g = 0; g < 2; ++g)
#pragma unroll
      for (int r = 0; r < 4; ++r) {
        float mo = __shfl_xor(ml[g][r], off);
        float lo = __shfl_xor(ll[g][r], off);
        float mn = fmaxf(ml[g][r], mo);
        ll[g][r] = ll[g][r] * fexp2(ml[g][r] - mn) + lo * fexp2(mo - mn);
        ml[g][r] = mn;
      }
  // merge across the 4 waves (key quarters) via LDS, once
  if (col == 0) {
#pragma unroll
    for (int g = 0; g < 2; ++g)
#pragma unroll
      for (int r = 0; r < 4; ++r) {
        int qr = g * 16 + quad * 4 + r;
        mbuf[w * 32 + qr] = ml[g][r];
        lbuf[w * 32 + qr] = ll[g][r];
      }
  }
  __syncthreads();
  float mf[2][4], c1[2][4];
#pragma unroll
  for (int g = 0; g < 2; ++g)
#pragma unroll
    for (int r = 0; r < 4; ++r) {
      int qr = g * 16 + quad * 4 + r;
      float M = -3e38f, L = 0.f;
#pragma unroll
      for (int ww = 0; ww < 4; ++ww) {
        float mo = mbuf[ww * 32 + qr];
        float lo = lbuf[ww * 32 + qr];
        float mn = fmaxf(M, mo);
        L = L * fexp2(M - mn) + lo * fexp2(mo - mn);
        M = mn;
      }
      mf[g][r] = M;
      c1[g][r] = a1 / L;
    }

  // =========================== PASS 2: P, O ================================
  f32x4 o[2][4];
#pragma unroll
  for (int g = 0; g < 2; ++g)
#pragma unroll
    for (int j = 0; j < 4; ++j) o[g][j] = (f32x4){0.f, 0.f, 0.f, 0.f};

  // P write: [32 q][64 keys] bf16, 16B-slot XOR swizzle within 128B rows
  auto pwrite = [&](u16* Pn, const f32x4* s) {
#pragma unroll
    for (int g = 0; g < 2; ++g)
#pragma unroll
      for (int r = 0; r < 4; ++r) {
        float sv = s[g][r];
        float rl = sv > 0.f ? sv * sv : 0.f;
        float p = c1[g][r] * fexp2(sv - mf[g][r]) + a2p * rl;
        int qr = g * 16 + quad * 4 + r;
        int slot = ((w * 2 + (col >> 3)) ^ qr) & 7;
        Pn[qr * 64 + slot * 8 + (col & 7)] = f2bf(p);
      }
  };

  bf16x8 bk[8], bv[8];
  // prologue: bk(0), S(0), P write -> Pb0, bv(0), barrier
#pragma unroll
  for (int kk = 0; kk < 8; ++kk)
    bk[kk] = *(const bf16x8*)(kbase + kk * 32);
  {
    f32x4 s[2];
    s[0] = (f32x4){0.f, 0.f, 0.f, 0.f};
    s[1] = (f32x4){0.f, 0.f, 0.f, 0.f};
#pragma unroll
    for (int kk = 0; kk < 8; ++kk) {
      s[0] = __builtin_amdgcn_mfma_f32_16x16x32_bf16(aq[0][kk], bk[kk], s[0], 0, 0, 0);
      s[1] = __builtin_amdgcn_mfma_f32_16x16x32_bf16(aq[1][kk], bk[kk], s[1], 0, 0, 0);
    }
    pwrite(Pb0, s);
  }
#pragma unroll
  for (int j = 0; j < 4; ++j)
#pragma unroll
    for (int ks = 0; ks < 2; ++ks)
      bv[j * 2 + ks] = *(const bf16x8*)(vbase + (size_t)j * 16 * NTOK + ks * 32);
  asm volatile("s_waitcnt lgkmcnt(0)\n\ts_barrier" ::: "memory");
  __builtin_amdgcn_sched_barrier(0);

  for (int t = 0; t < 64; ++t) {
    u16* Pc = (t & 1) ? Pb1 : Pb0;
    // pa reads (swizzled)
    bf16x8 pa[2][2];
#pragma unroll
    for (int g = 0; g < 2; ++g)
#pragma unroll
      for (int ks = 0; ks < 2; ++ks)
        pa[g][ks] = *(const bf16x8*)&Pc[(g * 16 + col) * 64 +
                                        (((quad + ks * 4) ^ (col & 7)) & 7) * 8];
    // bk(t+1) issue (hidden under PV)
    if (t < 63) {
#pragma unroll
      for (int kk = 0; kk < 8; ++kk)
        bk[kk] = *(const bf16x8*)(kbase + (size_t)(t + 1) * 16384 + kk * 32);
    }
    // PV(t): 16 MFMAs, full 64 keys x this wave's 64 channels x 32 q
#pragma unroll
    for (int g = 0; g < 2; ++g)
#pragma unroll
      for (int j = 0; j < 4; ++j) {
        o[g][j] = __builtin_amdgcn_mfma_f32_16x16x32_bf16(pa[g][0], bv[j * 2 + 0], o[g][j], 0, 0, 0);
        o[g][j] = __builtin_amdgcn_mfma_f32_16x16x32_bf16(pa[g][1], bv[j * 2 + 1], o[g][j], 0, 0, 0);
      }
    if (t < 63) {
      // bv(t+1) issue (hidden under S)
#pragma unroll
      for (int j = 0; j < 4; ++j)
#pragma unroll
        for (int ks = 0; ks < 2; ++ks)
          bv[j * 2 + ks] = *(const bf16x8*)(vbase + (size_t)j * 16 * NTOK +
                                            (size_t)(t + 1) * 64 + ks * 32);
      // S(t+1): 16 MFMAs on this wave's 16 keys
      f32x4 s2[2];
      s2[0] = (f32x4){0.f, 0.f, 0.f, 0.f};
      s2[1] = (f32x4){0.f, 0.f, 0.f, 0.f};
#pragma unroll
      for (int kk = 0; kk < 8; ++kk) {
        s2[0] = __builtin_amdgcn_mfma_f32_16x16x32_bf16(aq[0][kk], bk[kk], s2[0], 0, 0, 0);
        s2[1] = __builtin_amdgcn_mfma_f32_16x16x32_bf16(aq[1][kk], bk[kk], s2[1], 0, 0, 0);
      }
      pwrite((t & 1) ? Pb0 : Pb1, s2);
      asm volatile("s_waitcnt lgkmcnt(0)\n\ts_barrier" ::: "memory");
      __builtin_amdgcn_sched_barrier(0);
    }
  }

  // ---- epilogue: residual + transpose to [c][n] ----
  __syncthreads();   // all waves done with P before otile overlays it
#pragma unroll
  for (int g = 0; g < 2; ++g)
#pragma unroll
    for (int j = 0; j < 4; ++j) {
      int c = w * 64 + j * 16 + col;
      float4 v4;
      float* vv = (float*)&v4;
#pragma unroll
      for (int r = 0; r < 4; ++r) {
        int row = g * 16 + quad * 4 + r;
        vv[r] = o[g][j][r] + bf2f(xng[((size_t)b * NTOK + q0 + row) * CDIM + c]);
      }
      *(float4*)&otile[(size_t)c * 36 + g * 16 + quad * 4] = v4;
    }
  __syncthreads();

#pragma unroll
  for (int it = 0; it < 8; ++it) {
    int c  = it * 32 + (tid >> 3);
    int ch = tid & 7;
    *(float4*)&outg[((size_t)b * CDIM + c) * NTOK + q0 + ch * 4] =
        *(const float4*)&otile[(size_t)c * 36 + ch * 4];
  }
}

// ---------------------------------------------------------------------------
extern "C" void kernel_launch(void* const* d_in, const int* in_sizes, int n_in,
                              void* d_out, int out_size, void* d_ws, size_t ws_size,
                              hipStream_t stream) {
  const float* x     = (const float*)d_in[0];
  const float* gamma = (const float*)d_in[1];
  const float* beta  = (const float*)d_in[2];
  const float* Wq    = (const float*)d_in[3];
  const float* Wk    = (const float*)d_in[4];
  const float* Wv    = (const float*)d_in[5];
  const float* w1    = (const float*)d_in[6];
  const float* w2    = (const float*)d_in[7];
  float* out = (float*)d_out;

  char* ws = (char*)d_ws;
  size_t off = 0;
  u16* xn  = (u16*)(ws + off); off += (size_t)BATCH * NTOK * CDIM * 2;
  u16* WT3 = (u16*)(ws + off); off += (size_t)3 * CDIM * CDIM * 2;   // [768][256]
  u16* Qb  = (u16*)(ws + off); off += (size_t)BATCH * NTOK * CDIM * 2;
  u16* Kb  = (u16*)(ws + off); off += (size_t)BATCH * NTOK * CDIM * 2;
  u16* VT  = (u16*)(ws + off); off += (size_t)BATCH * NTOK * CDIM * 2;  // [b][c][n]

  const float LOG2E = 1.4426950408889634f;

  // 1) LayerNorm -> xn bf16 [B*N, C]
  ln_kernel<<<dim3(BATCH * (NTOK / 32)), 256, 0, stream>>>(x, gamma, beta, xn);

  // 2) stacked transposed weights (Wq pre-scaled by log2e -> exp2-domain S)
  wt_kernel<<<dim3(8, 8), dim3(32, 8), 0, stream>>>(Wq, WT3, LOG2E);
  wt_kernel<<<dim3(8, 8), dim3(32, 8), 0, stream>>>(Wk, WT3 + 256 * 256, 1.0f);
  wt_kernel<<<dim3(8, 8), dim3(32, 8), 0, stream>>>(Wv, WT3 + 512 * 256, 1.0f);

  // 3) fused Q/K/V projection (one launch)
  qkv_kernel<<<dim3(12, 128), 256, 0, stream>>>(xn, WT3, Qb, Kb, VT);

  // 4) fused attention (two-pass, direct-from-L2) + mix + residual + transpose
  fa_kernel<<<dim3(512), 256, 0, stream>>>(Qb, Kb, VT, xn, w1, w2, out);
}

// Round 3
// 457.526 us; speedup vs baseline: 1.0077x; 1.0077x over previous
//
#include <hip/hip_runtime.h>
#include <hip/hip_bf16.h>
#include <cstdint>

typedef unsigned short u16;
typedef __attribute__((ext_vector_type(8))) short bf16x8;
typedef __attribute__((ext_vector_type(4))) float f32x4;

#define BATCH 4
#define CDIM 256
#define NTOK 4096   // H*W

__device__ inline float fexp2(float x) { return __builtin_amdgcn_exp2f(x); }

__device__ inline u16 f2bf(float f) {
  union { float f; uint32_t u; } un; un.f = f;
  uint32_t u = un.u;
  u += 0x7fffu + ((u >> 16) & 1u);
  return (u16)(u >> 16);
}
__device__ inline float bf2f(u16 h) {
  union { uint32_t u; float f; } un; un.u = ((uint32_t)h) << 16; return un.f;
}

// ---------------------------------------------------------------------------
// LayerNorm: x [B, C, N] -> xn bf16 [B*N, C]
// ---------------------------------------------------------------------------
__global__ __launch_bounds__(256) void ln_kernel(const float* __restrict__ x,
                                                 const float* __restrict__ gamma,
                                                 const float* __restrict__ beta,
                                                 u16* __restrict__ xn) {
  __shared__ float tile[CDIM][33];
  __shared__ float reds[8][32];
  __shared__ float reds2[8][32];
  __shared__ float mu_s[32], rs_s[32];

  int b  = blockIdx.x >> 7;
  int n0 = (blockIdx.x & 127) * 32;
  const float* xb = x + (size_t)b * CDIM * NTOK;

  int t = threadIdx.x & 31;
  int g = threadIdx.x >> 5;

  for (int c = g; c < CDIM; c += 8)
    tile[c][t] = xb[(size_t)c * NTOK + n0 + t];
  __syncthreads();

  float s = 0.f, s2 = 0.f;
  for (int c = g * 32; c < g * 32 + 32; ++c) {
    float v = tile[c][t];
    s += v; s2 += v * v;
  }
  reds[g][t] = s; reds2[g][t] = s2;
  __syncthreads();
  if (threadIdx.x < 32) {
    float ts = 0.f, ts2 = 0.f;
    for (int gg = 0; gg < 8; ++gg) { ts += reds[gg][threadIdx.x]; ts2 += reds2[gg][threadIdx.x]; }
    float mu = ts / CDIM;
    float var = ts2 / CDIM - mu * mu;
    mu_s[threadIdx.x] = mu;
    rs_s[threadIdx.x] = rsqrtf(var + 1e-5f);
  }
  __syncthreads();

  int c = threadIdx.x;
  float gam = gamma[c], bet = beta[c];
  u16* out = xn + ((size_t)b * NTOK + n0) * CDIM;
  for (int tt = 0; tt < 32; ++tt) {
    float v = tile[c][tt];
    float y = (v - mu_s[tt]) * rs_s[tt] * gam + bet;
    out[(size_t)tt * CDIM + c] = f2bf(y);
  }
}

// ---------------------------------------------------------------------------
// W [K, Cout] fp32 -> WT bf16 [Cout, K], optional scale (log2e for Wq)
// ---------------------------------------------------------------------------
__global__ __launch_bounds__(256) void wt_kernel(const float* __restrict__ W,
                                                 u16* __restrict__ WT,
                                                 float scale) {
  __shared__ float tile[32][33];
  int i0 = blockIdx.y * 32;
  int j0 = blockIdx.x * 32;
  int tx = threadIdx.x, ty = threadIdx.y;
  for (int r = ty; r < 32; r += 8)
    tile[r][tx] = W[(size_t)(i0 + r) * CDIM + j0 + tx];
  __syncthreads();
  for (int r = ty; r < 32; r += 8)
    WT[(size_t)(j0 + r) * CDIM + i0 + tx] = f2bf(tile[tx][r] * scale);
}

// ---------------------------------------------------------------------------
// Fused QKV projection (unchanged)
// ---------------------------------------------------------------------------
__global__ __launch_bounds__(256) void qkv_kernel(const u16* __restrict__ A,
                                                  const u16* __restrict__ B3,
                                                  u16* __restrict__ Qb,
                                                  u16* __restrict__ Kb,
                                                  u16* __restrict__ VT) {
  constexpr int BM = 128, BN = 64, BK = 32;
  __shared__ u16 shA[BM][BK + 8];
  __shared__ u16 shB[BN][BK + 8];

  int m0 = blockIdx.y * BM;
  int n0 = blockIdx.x * BN;

  int tid  = threadIdx.x;
  int lane = tid & 63;
  int wave = tid >> 6;
  int wm = wave >> 1, wn = wave & 1;
  int col  = lane & 15;
  int quad = lane >> 4;

  f32x4 acc[4][2];
#pragma unroll
  for (int i = 0; i < 4; ++i)
#pragma unroll
    for (int j = 0; j < 2; ++j) acc[i][j] = (f32x4){0.f, 0.f, 0.f, 0.f};

  for (int kb = 0; kb < CDIM; kb += BK) {
    __syncthreads();
#pragma unroll
    for (int c = tid; c < BM * BK / 8; c += 256) {
      int row = c >> 2, kc = c & 3;
      *(uint4*)&shA[row][kc * 8] = *(const uint4*)&A[(size_t)(m0 + row) * CDIM + kb + kc * 8];
    }
#pragma unroll
    for (int c = tid; c < BN * BK / 8; c += 256) {
      int row = c >> 2, kc = c & 3;
      *(uint4*)&shB[row][kc * 8] = *(const uint4*)&B3[(size_t)(n0 + row) * CDIM + kb + kc * 8];
    }
    __syncthreads();

    bf16x8 af[4], bfv[2];
#pragma unroll
    for (int i = 0; i < 4; ++i)
      af[i] = *(const bf16x8*)&shA[wm * 64 + i * 16 + col][quad * 8];
#pragma unroll
    for (int j = 0; j < 2; ++j)
      bfv[j] = *(const bf16x8*)&shB[wn * 32 + j * 16 + col][quad * 8];
#pragma unroll
    for (int i = 0; i < 4; ++i)
#pragma unroll
      for (int j = 0; j < 2; ++j)
        acc[i][j] = __builtin_amdgcn_mfma_f32_16x16x32_bf16(af[i], bfv[j], acc[i][j], 0, 0, 0);
  }

  int mode = n0 >> 8;   // 0:Q 1:K 2:V (block-uniform)
  int r0 = quad * 4;
#pragma unroll
  for (int i = 0; i < 4; ++i) {
    int mbase = m0 + wm * 64 + i * 16 + r0;
#pragma unroll
    for (int j = 0; j < 2; ++j) {
      int n = n0 + wn * 32 + j * 16 + col;
#pragma unroll
      for (int r = 0; r < 4; ++r) {
        int m = mbase + r;
        float v = acc[i][j][r];
        if (mode == 0) {
          Qb[(size_t)m * CDIM + n] = f2bf(v);
        } else if (mode == 1) {
          Kb[(size_t)m * CDIM + (n - 256)] = f2bf(v);
        } else {
          int cv = n - 512, bb = m >> 12, nt = m & 4095;
          VT[((size_t)bb * CDIM + cv) * NTOK + nt] = f2bf(v);
        }
      }
    }
  }
}

// ---------------------------------------------------------------------------
// Fused attention, TWO-PASS exact softmax, DIRECT-FROM-L2 operands.
// Identical structure to R2, SCRATCH-PROOFED: no pointer-param lambdas;
// pass-1 compute and P-write are _Pragma("unroll") macros on named register
// arrays (rule #20: pointer params pinned kf0/kf1/s to scratch -> 96 VGPR,
// 367us. This version must report ~200+ VGPR and no scratch).
// ---------------------------------------------------------------------------

// Online-softmax update using kf bank KF (kf0 or kf1), named array.
#define P1_STEP(KF)                                                            \
  {                                                                            \
    f32x4 s0 = (f32x4){0.f, 0.f, 0.f, 0.f};                                    \
    f32x4 s1 = (f32x4){0.f, 0.f, 0.f, 0.f};                                    \
    _Pragma("unroll")                                                          \
    for (int kk = 0; kk < 8; ++kk) {                                           \
      s0 = __builtin_amdgcn_mfma_f32_16x16x32_bf16(aq[0][kk], KF[kk], s0, 0, 0, 0); \
      s1 = __builtin_amdgcn_mfma_f32_16x16x32_bf16(aq[1][kk], KF[kk], s1, 0, 0, 0); \
    }                                                                          \
    float mn0[4], mn1[4];                                                      \
    bool chg = false;                                                          \
    _Pragma("unroll")                                                          \
    for (int r = 0; r < 4; ++r) {                                              \
      mn0[r] = fmaxf(ml[0][r], s0[r]);                                         \
      mn1[r] = fmaxf(ml[1][r], s1[r]);                                         \
      chg = chg || (mn0[r] > ml[0][r]) || (mn1[r] > ml[1][r]);                 \
    }                                                                          \
    if (__any(chg)) {                                                          \
      _Pragma("unroll")                                                        \
      for (int r = 0; r < 4; ++r) {                                            \
        ll[0][r] = ll[0][r] * fexp2(ml[0][r] - mn0[r]) + fexp2(s0[r] - mn0[r]);\
        ml[0][r] = mn0[r];                                                     \
        ll[1][r] = ll[1][r] * fexp2(ml[1][r] - mn1[r]) + fexp2(s1[r] - mn1[r]);\
        ml[1][r] = mn1[r];                                                     \
      }                                                                        \
    } else {                                                                   \
      _Pragma("unroll")                                                        \
      for (int r = 0; r < 4; ++r) {                                            \
        ll[0][r] += fexp2(s0[r] - ml[0][r]);                                   \
        ll[1][r] += fexp2(s1[r] - ml[1][r]);                                   \
      }                                                                        \
    }                                                                          \
  }

// S from bk bank, into named s0/s1.
#define S_COMPUTE(BK_)                                                         \
  {                                                                            \
    s0 = (f32x4){0.f, 0.f, 0.f, 0.f};                                          \
    s1 = (f32x4){0.f, 0.f, 0.f, 0.f};                                          \
    _Pragma("unroll")                                                          \
    for (int kk = 0; kk < 8; ++kk) {                                           \
      s0 = __builtin_amdgcn_mfma_f32_16x16x32_bf16(aq[0][kk], BK_[kk], s0, 0, 0, 0); \
      s1 = __builtin_amdgcn_mfma_f32_16x16x32_bf16(aq[1][kk], BK_[kk], s1, 0, 0, 0); \
    }                                                                          \
  }

// Combined P from named s0/s1 into LDS buffer PN (runtime LDS ptr is fine).
#define P_WRITE(PN)                                                            \
  {                                                                            \
    _Pragma("unroll")                                                          \
    for (int r = 0; r < 4; ++r) {                                              \
      float sv0 = s0[r];                                                       \
      float rl0 = sv0 > 0.f ? sv0 * sv0 : 0.f;                                 \
      float p0 = c1[0][r] * fexp2(sv0 - mf[0][r]) + a2p * rl0;                 \
      int qr0 = quad * 4 + r;                                                  \
      int sl0 = ((w * 2 + (col >> 3)) ^ qr0) & 7;                              \
      (PN)[qr0 * 64 + sl0 * 8 + (col & 7)] = f2bf(p0);                         \
      float sv1 = s1[r];                                                       \
      float rl1 = sv1 > 0.f ? sv1 * sv1 : 0.f;                                 \
      float p1 = c1[1][r] * fexp2(sv1 - mf[1][r]) + a2p * rl1;                 \
      int qr1 = 16 + quad * 4 + r;                                             \
      int sl1 = ((w * 2 + (col >> 3)) ^ qr1) & 7;                              \
      (PN)[qr1 * 64 + sl1 * 8 + (col & 7)] = f2bf(p1);                         \
    }                                                                          \
  }

__global__ __launch_bounds__(256, 2) void fa_kernel(const u16* __restrict__ Qg,
                                                    const u16* __restrict__ Kg,
                                                    const u16* __restrict__ Vtg,
                                                    const u16* __restrict__ xng,
                                                    const float* __restrict__ w1p,
                                                    const float* __restrict__ w2p,
                                                    float* __restrict__ outg) {
  // epilogue otile [256][36] f32 = 36864 B dominates; P/stat usage is smaller
  __shared__ __align__(16) char smem[36864];
  float* otile = (float*)smem;
  u16* Pb0 = (u16*)smem;                 // [32][64] bf16, 16B-slot XOR swizzle
  u16* Pb1 = Pb0 + 2048;
  float* mbuf = (float*)(smem + 8192);   // [4 waves][32 q]
  float* lbuf = mbuf + 128;

  int b  = blockIdx.x & 3;               // XCD swizzle: same XCD -> same batch
  int q0 = (blockIdx.x >> 2) * 32;

  const u16* Q  = Qg  + (size_t)b * NTOK * CDIM;
  const u16* K  = Kg  + (size_t)b * NTOK * CDIM;
  const u16* Vt = Vtg + (size_t)b * NTOK * CDIM;

  int tid  = threadIdx.x;
  int lane = tid & 63;
  int w    = tid >> 6;                   // wave = key quarter
  int col = lane & 15, quad = lane >> 4;

  float e1 = __expf(w1p[0]), e2 = __expf(w2p[0]);
  float a1 = e1 / (e1 + e2), a2 = e2 / (e1 + e2);
  float a2p = a2 * 0.4804530139182014f;  // a2 * ln2^2 (S in exp2 domain)

  // ---- Q A-frags for BOTH q-groups (64 VGPR), live through both passes ----
  bf16x8 aq[2][8];
#pragma unroll
  for (int g = 0; g < 2; ++g)
#pragma unroll
    for (int kk = 0; kk < 8; ++kk)
      aq[g][kk] = *(const bf16x8*)&Q[(size_t)(q0 + g * 16 + col) * CDIM + kk * 32 + quad * 8];

  // per-lane global bases: K rows = keys (this wave's 16), VT rows = channels
  const u16* kbase = K  + (size_t)(w * 16 + col) * CDIM + quad * 8;
  const u16* vbase = Vt + (size_t)(w * 64 + col) * NTOK + quad * 8;

  // =========================== PASS 1: m, l ================================
  float ml[2][4], ll[2][4];
#pragma unroll
  for (int g = 0; g < 2; ++g)
#pragma unroll
    for (int r = 0; r < 4; ++r) { ml[g][r] = -3e38f; ll[g][r] = 0.f; }

  bf16x8 kf0[8], kf1[8];
#pragma unroll
  for (int kk = 0; kk < 8; ++kk)
    kf0[kk] = *(const bf16x8*)(kbase + kk * 32);

  for (int t = 0; t < 64; t += 2) {
#pragma unroll
    for (int kk = 0; kk < 8; ++kk)
      kf1[kk] = *(const bf16x8*)(kbase + (size_t)(t + 1) * 16384 + kk * 32);
    P1_STEP(kf0)
    if (t + 2 < 64) {
#pragma unroll
      for (int kk = 0; kk < 8; ++kk)
        kf0[kk] = *(const bf16x8*)(kbase + (size_t)(t + 2) * 16384 + kk * 32);
    }
    P1_STEP(kf1)
  }

  // merge across the 16 cols of this wave (keys within quarter)
#pragma unroll
  for (int off = 1; off < 16; off <<= 1)
#pragma unroll
    for (int g = 0; g < 2; ++g)
#pragma unroll
      for (int r = 0; r < 4; ++r) {
        float mo = __shfl_xor(ml[g][r], off);
        float lo = __shfl_xor(ll[g][r], off);
        float mn = fmaxf(ml[g][r], mo);
        ll[g][r] = ll[g][r] * fexp2(ml[g][r] - mn) + lo * fexp2(mo - mn);
        ml[g][r] = mn;
      }
  // merge across the 4 waves (key quarters) via LDS, once
  if (col == 0) {
#pragma unroll
    for (int g = 0; g < 2; ++g)
#pragma unroll
      for (int r = 0; r < 4; ++r) {
        int qr = g * 16 + quad * 4 + r;
        mbuf[w * 32 + qr] = ml[g][r];
        lbuf[w * 32 + qr] = ll[g][r];
      }
  }
  __syncthreads();
  float mf[2][4], c1[2][4];
#pragma unroll
  for (int g = 0; g < 2; ++g)
#pragma unroll
    for (int r = 0; r < 4; ++r) {
      int qr = g * 16 + quad * 4 + r;
      float M = -3e38f, L = 0.f;
#pragma unroll
      for (int ww = 0; ww < 4; ++ww) {
        float mo = mbuf[ww * 32 + qr];
        float lo = lbuf[ww * 32 + qr];
        float mn = fmaxf(M, mo);
        L = L * fexp2(M - mn) + lo * fexp2(mo - mn);
        M = mn;
      }
      mf[g][r] = M;
      c1[g][r] = a1 / L;
    }

  // =========================== PASS 2: P, O ================================
  f32x4 o[2][4];
#pragma unroll
  for (int g = 0; g < 2; ++g)
#pragma unroll
    for (int j = 0; j < 4; ++j) o[g][j] = (f32x4){0.f, 0.f, 0.f, 0.f};

  bf16x8 bk[8], bv[8];
  // prologue: bk(0), S(0), P write -> Pb0, bv(0), barrier
#pragma unroll
  for (int kk = 0; kk < 8; ++kk)
    bk[kk] = *(const bf16x8*)(kbase + kk * 32);
  {
    f32x4 s0, s1;
    S_COMPUTE(bk)
    P_WRITE(Pb0)
  }
#pragma unroll
  for (int j = 0; j < 4; ++j)
#pragma unroll
    for (int ks = 0; ks < 2; ++ks)
      bv[j * 2 + ks] = *(const bf16x8*)(vbase + (size_t)j * 16 * NTOK + ks * 32);
  asm volatile("s_waitcnt lgkmcnt(0)\n\ts_barrier" ::: "memory");
  __builtin_amdgcn_sched_barrier(0);

  for (int t = 0; t < 64; ++t) {
    u16* Pc = (t & 1) ? Pb1 : Pb0;
    // pa reads (swizzled)
    bf16x8 pa[2][2];
#pragma unroll
    for (int g = 0; g < 2; ++g)
#pragma unroll
      for (int ks = 0; ks < 2; ++ks)
        pa[g][ks] = *(const bf16x8*)&Pc[(g * 16 + col) * 64 +
                                        (((quad + ks * 4) ^ (col & 7)) & 7) * 8];
    // bk(t+1) issue (hidden under PV)
    if (t < 63) {
#pragma unroll
      for (int kk = 0; kk < 8; ++kk)
        bk[kk] = *(const bf16x8*)(kbase + (size_t)(t + 1) * 16384 + kk * 32);
    }
    // PV(t): 16 MFMAs, full 64 keys x this wave's 64 channels x 32 q
#pragma unroll
    for (int g = 0; g < 2; ++g)
#pragma unroll
      for (int j = 0; j < 4; ++j) {
        o[g][j] = __builtin_amdgcn_mfma_f32_16x16x32_bf16(pa[g][0], bv[j * 2 + 0], o[g][j], 0, 0, 0);
        o[g][j] = __builtin_amdgcn_mfma_f32_16x16x32_bf16(pa[g][1], bv[j * 2 + 1], o[g][j], 0, 0, 0);
      }
    if (t < 63) {
      // bv(t+1) issue (hidden under S)
#pragma unroll
      for (int j = 0; j < 4; ++j)
#pragma unroll
        for (int ks = 0; ks < 2; ++ks)
          bv[j * 2 + ks] = *(const bf16x8*)(vbase + (size_t)j * 16 * NTOK +
                                            (size_t)(t + 1) * 64 + ks * 32);
      // S(t+1): 16 MFMAs on this wave's 16 keys
      f32x4 s0, s1;
      S_COMPUTE(bk)
      P_WRITE((t & 1) ? Pb0 : Pb1)
      asm volatile("s_waitcnt lgkmcnt(0)\n\ts_barrier" ::: "memory");
      __builtin_amdgcn_sched_barrier(0);
    }
  }

  // ---- epilogue: residual + transpose to [c][n] ----
  __syncthreads();   // all waves done with P before otile overlays it
#pragma unroll
  for (int g = 0; g < 2; ++g)
#pragma unroll
    for (int j = 0; j < 4; ++j) {
      int c = w * 64 + j * 16 + col;
      float4 v4;
      float* vv = (float*)&v4;
#pragma unroll
      for (int r = 0; r < 4; ++r) {
        int row = g * 16 + quad * 4 + r;
        vv[r] = o[g][j][r] + bf2f(xng[((size_t)b * NTOK + q0 + row) * CDIM + c]);
      }
      *(float4*)&otile[(size_t)c * 36 + g * 16 + quad * 4] = v4;
    }
  __syncthreads();

#pragma unroll
  for (int it = 0; it < 8; ++it) {
    int c  = it * 32 + (tid >> 3);
    int ch = tid & 7;
    *(float4*)&outg[((size_t)b * CDIM + c) * NTOK + q0 + ch * 4] =
        *(const float4*)&otile[(size_t)c * 36 + ch * 4];
  }
}

// ---------------------------------------------------------------------------
extern "C" void kernel_launch(void* const* d_in, const int* in_sizes, int n_in,
                              void* d_out, int out_size, void* d_ws, size_t ws_size,
                              hipStream_t stream) {
  const float* x     = (const float*)d_in[0];
  const float* gamma = (const float*)d_in[1];
  const float* beta  = (const float*)d_in[2];
  const float* Wq    = (const float*)d_in[3];
  const float* Wk    = (const float*)d_in[4];
  const float* Wv    = (const float*)d_in[5];
  const float* w1    = (const float*)d_in[6];
  const float* w2    = (const float*)d_in[7];
  float* out = (float*)d_out;

  char* ws = (char*)d_ws;
  size_t off = 0;
  u16* xn  = (u16*)(ws + off); off += (size_t)BATCH * NTOK * CDIM * 2;
  u16* WT3 = (u16*)(ws + off); off += (size_t)3 * CDIM * CDIM * 2;   // [768][256]
  u16* Qb  = (u16*)(ws + off); off += (size_t)BATCH * NTOK * CDIM * 2;
  u16* Kb  = (u16*)(ws + off); off += (size_t)BATCH * NTOK * CDIM * 2;
  u16* VT  = (u16*)(ws + off); off += (size_t)BATCH * NTOK * CDIM * 2;  // [b][c][n]

  const float LOG2E = 1.4426950408889634f;

  // 1) LayerNorm -> xn bf16 [B*N, C]
  ln_kernel<<<dim3(BATCH * (NTOK / 32)), 256, 0, stream>>>(x, gamma, beta, xn);

  // 2) stacked transposed weights (Wq pre-scaled by log2e -> exp2-domain S)
  wt_kernel<<<dim3(8, 8), dim3(32, 8), 0, stream>>>(Wq, WT3, LOG2E);
  wt_kernel<<<dim3(8, 8), dim3(32, 8), 0, stream>>>(Wk, WT3 + 256 * 256, 1.0f);
  wt_kernel<<<dim3(8, 8), dim3(32, 8), 0, stream>>>(Wv, WT3 + 512 * 256, 1.0f);

  // 3) fused Q/K/V projection (one launch)
  qkv_kernel<<<dim3(12, 128), 256, 0, stream>>>(xn, WT3, Qb, Kb, VT);

  // 4) fused attention (two-pass, direct-from-L2) + mix + residual + transpose
  fa_kernel<<<dim3(512), 256, 0, stream>>>(Qb, Kb, VT, xn, w1, w2, out);
}